// Round 1
// baseline (1264.090 us; speedup 1.0000x reference)
//
#include <hip/hip_runtime.h>
#include <hip/hip_bf16.h>
#include <stdint.h>
#include <math.h>

#define NTOK 4096   // B*T
#define DDIM 1024
#define FDIM 4096
#define NEXP 8
#define NPAIR 8192  // NTOK * TOP_K

#define BM 128
#define BN 64
#define BK 64
#define APAD 72     // LDS row pitch (elems) = BK + 8 -> breaks phase conflicts on b128 reads
#define BPAD 72

using short8 = __attribute__((ext_vector_type(8))) short;
using f32x4  = __attribute__((ext_vector_type(4))) float;

__device__ __forceinline__ uint16_t f2bf(float f) {
    union { float f; uint32_t u; } v; v.f = f;
    uint32_t r = v.u + 0x7FFFu + ((v.u >> 16) & 1u);   // RNE
    return (uint16_t)(r >> 16);
}

// ---------------- router: fp32 logits, top-2, softmax weights, usage ----------------
__global__ void router_kernel(const float* __restrict__ x, const float* __restrict__ Wr,
                              float* __restrict__ usage_sum, int* __restrict__ counts,
                              int* __restrict__ top_e, float* __restrict__ top_w) {
    const int t = blockIdx.x;          // one wave per token
    const int lane = threadIdx.x;      // 64 lanes
    float acc[NEXP];
#pragma unroll
    for (int e = 0; e < NEXP; e++) acc[e] = 0.f;
    const float* xr = x + (size_t)t * DDIM;
    for (int d = lane; d < DDIM; d += 64) {
        float xv = xr[d];
        const float* wr = Wr + (size_t)d * NEXP;
#pragma unroll
        for (int e = 0; e < NEXP; e++) acc[e] += xv * wr[e];
    }
#pragma unroll
    for (int e = 0; e < NEXP; e++) {
#pragma unroll
        for (int off = 32; off > 0; off >>= 1) acc[e] += __shfl_xor(acc[e], off, 64);
    }
    if (lane == 0) {
        // top-2, first-occurrence tie-break (strict >) to match jax.lax.top_k
        int i0 = 0;
#pragma unroll
        for (int e = 1; e < NEXP; e++) if (acc[e] > acc[i0]) i0 = e;
        int i1 = -1;
#pragma unroll
        for (int e = 0; e < NEXP; e++) {
            if (e == i0) continue;
            if (i1 < 0 || acc[e] > acc[i1]) i1 = e;
        }
        float v0 = acc[i0], v1 = acc[i1];
        float e1 = __expf(v1 - v0);
        float inv = 1.f / (1.f + e1);
        top_e[t * 2 + 0] = i0; top_e[t * 2 + 1] = i1;
        top_w[t * 2 + 0] = inv; top_w[t * 2 + 1] = e1 * inv;
        atomicAdd(&counts[i0], 1);
        atomicAdd(&counts[i1], 1);
        // full softmax over 8 for load-balancing loss
        float m = acc[0];
#pragma unroll
        for (int e = 1; e < NEXP; e++) m = fmaxf(m, acc[e]);
        float p[NEXP]; float s = 0.f;
#pragma unroll
        for (int e = 0; e < NEXP; e++) { p[e] = __expf(acc[e] - m); s += p[e]; }
        float is = 1.f / s;
#pragma unroll
        for (int e = 0; e < NEXP; e++) atomicAdd(&usage_sum[e], p[e] * is);
    }
}

// ---------------- x fp32 -> bf16 ----------------
__global__ void xcast_kernel(const float* __restrict__ x, uint16_t* __restrict__ xb) {
    int i = blockIdx.x * 256 + threadIdx.x;        // one float4 per thread
    float4 v = ((const float4*)x)[i];
    ushort4 o;
    o.x = f2bf(v.x); o.y = f2bf(v.y); o.z = f2bf(v.z); o.w = f2bf(v.w);
    ((ushort4*)xb)[i] = o;
}

__global__ void offsets_kernel(const int* __restrict__ counts, int* __restrict__ offs) {
    if (threadIdx.x == 0) {
        int s = 0;
#pragma unroll
        for (int e = 0; e < NEXP; e++) { offs[e] = s; s += counts[e]; }
    }
}

__global__ void scatter_kernel(const int* __restrict__ top_e, const float* __restrict__ top_w,
                               const int* __restrict__ offs, int* __restrict__ fill,
                               int* __restrict__ pair_tok, float* __restrict__ pair_w) {
    int t = blockIdx.x * 256 + threadIdx.x;
    if (t >= NTOK) return;
#pragma unroll
    for (int k = 0; k < 2; k++) {
        int e = top_e[t * 2 + k];
        int pos = atomicAdd(&fill[e], 1);
        int pi = offs[e] + pos;
        pair_tok[pi] = t;
        pair_w[pi] = top_w[t * 2 + k];
    }
}

__global__ void loss_kernel(const float* __restrict__ usage_sum, float* __restrict__ out) {
    if (threadIdx.x == 0) {
        float s = 0.f;
#pragma unroll
        for (int e = 0; e < NEXP; e++) {
            float u = usage_sum[e] * (1.f / (float)NTOK);
            s += u * u;
        }
        out[(size_t)NTOK * DDIM] = (float)NEXP * s;
    }
}

// ---------------- pass A: h = silu(x@W1) * (x@W3) for gathered token tiles ----------------
__global__ __launch_bounds__(256, 2)
void expert_up_kernel(const uint16_t* __restrict__ x_bf,
                      const float* __restrict__ W1, const float* __restrict__ W3,
                      const int* __restrict__ counts, const int* __restrict__ offs,
                      const int* __restrict__ pair_tok, uint16_t* __restrict__ h) {
    const int e = blockIdx.z;
    const int tile = blockIdx.y;
    const int n0 = blockIdx.x * BN;
    const int cntAll = counts[e];
    if (tile * BM >= cntAll) return;
    const int cnt = min(BM, cntAll - tile * BM);
    const int pairBase = offs[e] + tile * BM;

    __shared__ uint16_t As[BM][APAD];
    __shared__ uint16_t B1s[BN][BPAD];
    __shared__ uint16_t B3s[BN][BPAD];

    const int tid = threadIdx.x;
    const int wave = tid >> 6;
    const int lane = tid & 63;
    const int quad = lane >> 4;
    const int lr = lane & 15;

    // A-staging: thread -> (row, k-half)
    const int ra = tid >> 1;
    const int ahalf = tid & 1;
    const int tokA = pair_tok[pairBase + min(ra, cnt - 1)];
    const uint16_t* aSrcBase = x_bf + (size_t)tokA * DDIM + ahalf * 32;

    // B-staging: thread -> (k-row, n-group of 16)
    const int kb = tid >> 2;
    const int ng = tid & 3;
    const float* w1Base = W1 + (size_t)e * DDIM * FDIM + n0 + ng * 16;
    const float* w3Base = W3 + (size_t)e * DDIM * FDIM + n0 + ng * 16;

    f32x4 accG[2][4], accU[2][4];
#pragma unroll
    for (int i = 0; i < 2; i++)
#pragma unroll
        for (int j = 0; j < 4; j++) {
            accG[i][j] = (f32x4){0.f, 0.f, 0.f, 0.f};
            accU[i][j] = (f32x4){0.f, 0.f, 0.f, 0.f};
        }

    for (int k0 = 0; k0 < DDIM; k0 += BK) {
        __syncthreads();
        {   // stage A: 64 B contiguous bf16 per thread
            const uint4* src = (const uint4*)(aSrcBase + k0);
            uint4 v0 = src[0], v1 = src[1], v2 = src[2], v3 = src[3];
            uint4* dst = (uint4*)&As[ra][ahalf * 32];
            dst[0] = v0; dst[1] = v1; dst[2] = v2; dst[3] = v3;
        }
        {   // stage B1/B3 transposed: global [k][n] fp32 -> LDS [n][k] bf16
            const float4* s1 = (const float4*)(w1Base + (size_t)(k0 + kb) * FDIM);
            float4 c0 = s1[0], c1 = s1[1], c2 = s1[2], c3 = s1[3];
            uint16_t* bc = &B1s[ng * 16][kb];
            bc[0*BPAD]=f2bf(c0.x); bc[1*BPAD]=f2bf(c0.y); bc[2*BPAD]=f2bf(c0.z); bc[3*BPAD]=f2bf(c0.w);
            bc[4*BPAD]=f2bf(c1.x); bc[5*BPAD]=f2bf(c1.y); bc[6*BPAD]=f2bf(c1.z); bc[7*BPAD]=f2bf(c1.w);
            bc[8*BPAD]=f2bf(c2.x); bc[9*BPAD]=f2bf(c2.y); bc[10*BPAD]=f2bf(c2.z); bc[11*BPAD]=f2bf(c2.w);
            bc[12*BPAD]=f2bf(c3.x); bc[13*BPAD]=f2bf(c3.y); bc[14*BPAD]=f2bf(c3.z); bc[15*BPAD]=f2bf(c3.w);
            const float4* s3 = (const float4*)(w3Base + (size_t)(k0 + kb) * FDIM);
            float4 d0 = s3[0], d1 = s3[1], d2 = s3[2], d3 = s3[3];
            uint16_t* dc = &B3s[ng * 16][kb];
            dc[0*BPAD]=f2bf(d0.x); dc[1*BPAD]=f2bf(d0.y); dc[2*BPAD]=f2bf(d0.z); dc[3*BPAD]=f2bf(d0.w);
            dc[4*BPAD]=f2bf(d1.x); dc[5*BPAD]=f2bf(d1.y); dc[6*BPAD]=f2bf(d1.z); dc[7*BPAD]=f2bf(d1.w);
            dc[8*BPAD]=f2bf(d2.x); dc[9*BPAD]=f2bf(d2.y); dc[10*BPAD]=f2bf(d2.z); dc[11*BPAD]=f2bf(d2.w);
            dc[12*BPAD]=f2bf(d3.x); dc[13*BPAD]=f2bf(d3.y); dc[14*BPAD]=f2bf(d3.z); dc[15*BPAD]=f2bf(d3.w);
        }
        __syncthreads();
#pragma unroll
        for (int kk = 0; kk < BK; kk += 32) {
            short8 af[2];
#pragma unroll
            for (int mi = 0; mi < 2; mi++)
                af[mi] = *(const short8*)&As[wave * 32 + mi * 16 + lr][kk + quad * 8];
#pragma unroll
            for (int ni = 0; ni < 4; ni++) {
                short8 b1 = *(const short8*)&B1s[ni * 16 + lr][kk + quad * 8];
                short8 b3 = *(const short8*)&B3s[ni * 16 + lr][kk + quad * 8];
#pragma unroll
                for (int mi = 0; mi < 2; mi++) {
                    accG[mi][ni] = __builtin_amdgcn_mfma_f32_16x16x32_bf16(af[mi], b1, accG[mi][ni], 0, 0, 0);
                    accU[mi][ni] = __builtin_amdgcn_mfma_f32_16x16x32_bf16(af[mi], b3, accU[mi][ni], 0, 0, 0);
                }
            }
        }
    }
    // epilogue: h = silu(gate) * up, bf16. C/D layout: col=lane&15, row=quad*4+reg
#pragma unroll
    for (int mi = 0; mi < 2; mi++) {
#pragma unroll
        for (int r = 0; r < 4; r++) {
            int rowLocal = wave * 32 + mi * 16 + quad * 4 + r;
            if (rowLocal < cnt) {
                uint16_t* dst = h + (size_t)(pairBase + rowLocal) * FDIM + n0 + lr;
#pragma unroll
                for (int ni = 0; ni < 4; ni++) {
                    float g = accG[mi][ni][r];
                    float u = accU[mi][ni][r];
                    float hv = (g / (1.f + __expf(-g))) * u;
                    dst[ni * 16] = f2bf(hv);
                }
            }
        }
    }
}

// ---------------- pass B: out += weight * (h @ W2) ----------------
__global__ __launch_bounds__(256, 2)
void expert_down_kernel(const uint16_t* __restrict__ h, const float* __restrict__ W2,
                        const int* __restrict__ counts, const int* __restrict__ offs,
                        const int* __restrict__ pair_tok, const float* __restrict__ pair_w,
                        float* __restrict__ out) {
    const int e = blockIdx.z;
    const int tile = blockIdx.y;
    const int n0 = blockIdx.x * BN;     // d columns
    const int cntAll = counts[e];
    if (tile * BM >= cntAll) return;
    const int cnt = min(BM, cntAll - tile * BM);
    const int pairBase = offs[e] + tile * BM;

    __shared__ uint16_t As[BM][APAD];
    __shared__ uint16_t Bs[BN][BPAD];

    const int tid = threadIdx.x;
    const int wave = tid >> 6;
    const int lane = tid & 63;
    const int quad = lane >> 4;
    const int lr = lane & 15;

    const int ra = tid >> 1;
    const int ahalf = tid & 1;
    const uint16_t* aSrcBase = h + (size_t)(pairBase + min(ra, cnt - 1)) * FDIM + ahalf * 32;

    const int kb = tid >> 2;
    const int ng = tid & 3;
    const float* w2Base = W2 + (size_t)e * FDIM * DDIM + n0 + ng * 16;

    f32x4 acc[2][4];
#pragma unroll
    for (int i = 0; i < 2; i++)
#pragma unroll
        for (int j = 0; j < 4; j++) acc[i][j] = (f32x4){0.f, 0.f, 0.f, 0.f};

    for (int k0 = 0; k0 < FDIM; k0 += BK) {
        __syncthreads();
        {
            const uint4* src = (const uint4*)(aSrcBase + k0);
            uint4 v0 = src[0], v1 = src[1], v2 = src[2], v3 = src[3];
            uint4* dst = (uint4*)&As[ra][ahalf * 32];
            dst[0] = v0; dst[1] = v1; dst[2] = v2; dst[3] = v3;
        }
        {
            const float4* s2 = (const float4*)(w2Base + (size_t)(k0 + kb) * DDIM);
            float4 c0 = s2[0], c1 = s2[1], c2 = s2[2], c3 = s2[3];
            uint16_t* bc = &Bs[ng * 16][kb];
            bc[0*BPAD]=f2bf(c0.x); bc[1*BPAD]=f2bf(c0.y); bc[2*BPAD]=f2bf(c0.z); bc[3*BPAD]=f2bf(c0.w);
            bc[4*BPAD]=f2bf(c1.x); bc[5*BPAD]=f2bf(c1.y); bc[6*BPAD]=f2bf(c1.z); bc[7*BPAD]=f2bf(c1.w);
            bc[8*BPAD]=f2bf(c2.x); bc[9*BPAD]=f2bf(c2.y); bc[10*BPAD]=f2bf(c2.z); bc[11*BPAD]=f2bf(c2.w);
            bc[12*BPAD]=f2bf(c3.x); bc[13*BPAD]=f2bf(c3.y); bc[14*BPAD]=f2bf(c3.z); bc[15*BPAD]=f2bf(c3.w);
        }
        __syncthreads();
#pragma unroll
        for (int kk = 0; kk < BK; kk += 32) {
            short8 af[2];
#pragma unroll
            for (int mi = 0; mi < 2; mi++)
                af[mi] = *(const short8*)&As[wave * 32 + mi * 16 + lr][kk + quad * 8];
#pragma unroll
            for (int ni = 0; ni < 4; ni++) {
                short8 b = *(const short8*)&Bs[ni * 16 + lr][kk + quad * 8];
#pragma unroll
                for (int mi = 0; mi < 2; mi++)
                    acc[mi][ni] = __builtin_amdgcn_mfma_f32_16x16x32_bf16(af[mi], b, acc[mi][ni], 0, 0, 0);
            }
        }
    }
#pragma unroll
    for (int mi = 0; mi < 2; mi++) {
#pragma unroll
        for (int r = 0; r < 4; r++) {
            int rowLocal = wave * 32 + mi * 16 + quad * 4 + r;
            if (rowLocal < cnt) {
                int pi = pairBase + rowLocal;
                int tok = pair_tok[pi];
                float w = pair_w[pi];
                float* dst = out + (size_t)tok * DDIM + n0 + lr;
#pragma unroll
                for (int ni = 0; ni < 4; ni++)
                    atomicAdd(&dst[ni * 16], acc[mi][ni][r] * w);
            }
        }
    }
}

extern "C" void kernel_launch(void* const* d_in, const int* in_sizes, int n_in,
                              void* d_out, int out_size, void* d_ws, size_t ws_size,
                              hipStream_t stream) {
    (void)in_sizes; (void)n_in; (void)ws_size;
    const float* x  = (const float*)d_in[0];
    const float* Wr = (const float*)d_in[1];
    const float* W1 = (const float*)d_in[2];
    const float* W3 = (const float*)d_in[3];
    const float* W2 = (const float*)d_in[4];
    float* out = (float*)d_out;

    char* ws = (char*)d_ws;
    float*    usage_sum = (float*)(ws + 0);
    int*      counts    = (int*)(ws + 64);
    int*      offs      = (int*)(ws + 128);
    int*      fill      = (int*)(ws + 192);
    int*      top_e     = (int*)(ws + 256);
    float*    top_w     = (float*)(ws + 256 + 4 * NPAIR);
    int*      pair_tok  = (int*)(ws + 256 + 8 * NPAIR);
    float*    pair_w    = (float*)(ws + 256 + 12 * NPAIR);
    uint16_t* x_bf      = (uint16_t*)(ws + 256 + 16 * NPAIR);                       // 8 MB
    uint16_t* h         = (uint16_t*)(ws + 256 + 16 * NPAIR + 2 * NTOK * DDIM);     // 67 MB

    hipMemsetAsync(ws, 0, 256, stream);                                   // usage/counts/fill
    hipMemsetAsync(d_out, 0, (size_t)out_size * sizeof(float), stream);   // out accumulators

    xcast_kernel<<<NTOK * DDIM / 1024, 256, 0, stream>>>(x, x_bf);
    router_kernel<<<NTOK, 64, 0, stream>>>(x, Wr, usage_sum, counts, top_e, top_w);
    offsets_kernel<<<1, 64, 0, stream>>>(counts, offs);
    scatter_kernel<<<NTOK / 256, 256, 0, stream>>>(top_e, top_w, offs, fill, pair_tok, pair_w);
    loss_kernel<<<1, 64, 0, stream>>>(usage_sum, out);

    dim3 gA(FDIM / BN, 32, NEXP);   // (f-tiles, max token-tiles, experts)
    expert_up_kernel<<<gA, 256, 0, stream>>>(x_bf, W1, W3, counts, offs, pair_tok, h);
    dim3 gB(DDIM / BN, 32, NEXP);   // (d-tiles, max token-tiles, experts)
    expert_down_kernel<<<gB, 256, 0, stream>>>(h, W2, counts, offs, pair_tok, pair_w, out);
}

// Round 2
// 836.477 us; speedup vs baseline: 1.5112x; 1.5112x over previous
//
#include <hip/hip_runtime.h>
#include <hip/hip_bf16.h>
#include <stdint.h>
#include <math.h>

#define NTOK 4096   // B*T
#define DDIM 1024
#define FDIM 4096
#define NEXP 8
#define NPAIR 8192  // NTOK * TOP_K

#define BM 256
#define BN 64
#define BK 64
#define APAD 72     // LDS row pitch (elems)
#define BPAD 72

#define RT_TPW 8                     // tokens per wave in router
#define RT_BLOCKS (NTOK / (4 * RT_TPW))   // 128

using short8 = __attribute__((ext_vector_type(8))) short;
using f32x4  = __attribute__((ext_vector_type(4))) float;

__device__ __forceinline__ uint16_t f2bf(float f) {
    union { float f; uint32_t u; } v; v.f = f;
    uint32_t r = v.u + 0x7FFFu + ((v.u >> 16) & 1u);   // RNE
    return (uint16_t)(r >> 16);
}

// ---------------- router: fp32 logits, top-2, softmax weights; block-local usage/counts ----------------
__global__ void router_kernel(const float* __restrict__ x, const float* __restrict__ Wr,
                              int* __restrict__ cnt_part, float* __restrict__ us_part,
                              int* __restrict__ top_e, float* __restrict__ top_w) {
    __shared__ float us[NEXP];
    __shared__ int cs[NEXP];
    const int tid = threadIdx.x;
    const int wv = tid >> 6;
    const int lane = tid & 63;
    if (tid < NEXP) { us[tid] = 0.f; cs[tid] = 0; }
    __syncthreads();

    for (int i = 0; i < RT_TPW; i++) {
        const int t = blockIdx.x * (4 * RT_TPW) + wv * RT_TPW + i;
        float acc[NEXP];
#pragma unroll
        for (int e = 0; e < NEXP; e++) acc[e] = 0.f;
        const float* xr = x + (size_t)t * DDIM;
        for (int d = lane; d < DDIM; d += 64) {
            float xv = xr[d];
            const float* wr = Wr + (size_t)d * NEXP;
#pragma unroll
            for (int e = 0; e < NEXP; e++) acc[e] += xv * wr[e];
        }
#pragma unroll
        for (int e = 0; e < NEXP; e++) {
#pragma unroll
            for (int off = 32; off > 0; off >>= 1) acc[e] += __shfl_xor(acc[e], off, 64);
        }
        if (lane == 0) {
            int i0 = 0;
#pragma unroll
            for (int e = 1; e < NEXP; e++) if (acc[e] > acc[i0]) i0 = e;
            int i1 = -1;
#pragma unroll
            for (int e = 0; e < NEXP; e++) {
                if (e == i0) continue;
                if (i1 < 0 || acc[e] > acc[i1]) i1 = e;
            }
            float v0 = acc[i0], v1 = acc[i1];
            float e1 = __expf(v1 - v0);
            float inv = 1.f / (1.f + e1);
            top_e[t * 2 + 0] = i0; top_e[t * 2 + 1] = i1;
            top_w[t * 2 + 0] = inv; top_w[t * 2 + 1] = e1 * inv;
            atomicAdd(&cs[i0], 1);
            atomicAdd(&cs[i1], 1);
            float m = acc[0];
#pragma unroll
            for (int e = 1; e < NEXP; e++) m = fmaxf(m, acc[e]);
            float p[NEXP]; float s = 0.f;
#pragma unroll
            for (int e = 0; e < NEXP; e++) { p[e] = __expf(acc[e] - m); s += p[e]; }
            float is = 1.f / s;
#pragma unroll
            for (int e = 0; e < NEXP; e++) atomicAdd(&us[e], p[e] * is);
        }
    }
    __syncthreads();
    if (tid < NEXP) {
        cnt_part[blockIdx.x * NEXP + tid] = cs[tid];
        us_part[blockIdx.x * NEXP + tid] = us[tid];
    }
}

// ---------------- finalize: counts, offsets, load-balancing loss ----------------
__global__ void finalize_kernel(const int* __restrict__ cnt_part, const float* __restrict__ us_part,
                                int* __restrict__ counts, int* __restrict__ offs,
                                float* __restrict__ out) {
    __shared__ int c[NEXP];
    __shared__ float u[NEXP];
    const int tid = threadIdx.x;
    if (tid < NEXP) {
        int csum = 0; float usum = 0.f;
        for (int b = 0; b < RT_BLOCKS; b++) {
            csum += cnt_part[b * NEXP + tid];
            usum += us_part[b * NEXP + tid];
        }
        counts[tid] = csum; c[tid] = csum; u[tid] = usum;
    }
    __syncthreads();
    if (tid == 0) {
        int s = 0; float l = 0.f;
#pragma unroll
        for (int e = 0; e < NEXP; e++) {
            offs[e] = s; s += c[e];
            float uu = u[e] * (1.f / (float)NTOK);
            l += uu * uu;
        }
        out[(size_t)NTOK * DDIM] = (float)NEXP * l;
    }
}

// ---------------- x fp32 -> bf16 ----------------
__global__ void xcast_kernel(const float* __restrict__ x, uint16_t* __restrict__ xb) {
    int i = blockIdx.x * 256 + threadIdx.x;
    float4 v = ((const float4*)x)[i];
    ushort4 o;
    o.x = f2bf(v.x); o.y = f2bf(v.y); o.z = f2bf(v.z); o.w = f2bf(v.w);
    ((ushort4*)xb)[i] = o;
}

// ---------------- transpose+cast: in [e][R][C] fp32 -> out [e][C][R] bf16 ----------------
__global__ void transpose_cast_kernel(const float* __restrict__ in, uint16_t* __restrict__ outp,
                                      int R, int C) {
    __shared__ uint16_t tile[32][36];
    const int e = blockIdx.z;
    const float* src = in + (size_t)e * R * C;
    uint16_t* dst = outp + (size_t)e * R * C;
    const int r0 = blockIdx.y * 32, c0 = blockIdx.x * 32;
    {
        int r = threadIdx.x >> 3, cq = threadIdx.x & 7;
        float4 v = *(const float4*)(src + (size_t)(r0 + r) * C + c0 + cq * 4);
        tile[cq * 4 + 0][r] = f2bf(v.x);
        tile[cq * 4 + 1][r] = f2bf(v.y);
        tile[cq * 4 + 2][r] = f2bf(v.z);
        tile[cq * 4 + 3][r] = f2bf(v.w);
    }
    __syncthreads();
    {
        int cc = threadIdx.x >> 3, rq = threadIdx.x & 7;
        ushort4 o = *(const ushort4*)&tile[cc][rq * 4];
        *(ushort4*)(dst + (size_t)(c0 + cc) * R + r0 + rq * 4) = o;
    }
}

// ---------------- scatter with block-aggregated ranks ----------------
__global__ void scatter_kernel(const int* __restrict__ top_e, const float* __restrict__ top_w,
                               const int* __restrict__ offs, int* __restrict__ fill,
                               int* __restrict__ pair_tok, float* __restrict__ pair_w) {
    __shared__ int lcnt[NEXP];
    __shared__ int lbase[NEXP];
    const int tid = threadIdx.x;
    const int t = blockIdx.x * 256 + tid;
    if (tid < NEXP) lcnt[tid] = 0;
    __syncthreads();
    int e0 = top_e[t * 2 + 0], e1 = top_e[t * 2 + 1];
    int r0 = atomicAdd(&lcnt[e0], 1);
    int r1 = atomicAdd(&lcnt[e1], 1);
    __syncthreads();
    if (tid < NEXP) lbase[tid] = atomicAdd(&fill[tid], lcnt[tid]);
    __syncthreads();
    int p0 = offs[e0] + lbase[e0] + r0;
    int p1 = offs[e1] + lbase[e1] + r1;
    pair_tok[p0] = t; pair_w[p0] = top_w[t * 2 + 0];
    pair_tok[p1] = t; pair_w[p1] = top_w[t * 2 + 1];
}

// ---------------- pass A: h = silu(x@W1) * (x@W3) ----------------
template<bool BF16W>
__global__ __launch_bounds__(256, 2)
void expert_up_kernel(const uint16_t* __restrict__ x_bf,
                      const float* __restrict__ W1f, const float* __restrict__ W3f,
                      const uint16_t* __restrict__ W1t, const uint16_t* __restrict__ W3t,
                      const int* __restrict__ counts, const int* __restrict__ offs,
                      const int* __restrict__ pair_tok, uint16_t* __restrict__ h) {
    const int e = blockIdx.z;
    const int tile = blockIdx.y;
    const int n0 = blockIdx.x * BN;
    const int cntAll = counts[e];
    if (tile * BM >= cntAll) return;
    const int cnt = min(BM, cntAll - tile * BM);
    const int pairBase = offs[e] + tile * BM;

    __shared__ uint16_t As[BM][APAD];
    __shared__ uint16_t B1s[BN][BPAD];
    __shared__ uint16_t B3s[BN][BPAD];

    const int tid = threadIdx.x;
    const int wave = tid >> 6;
    const int lane = tid & 63;
    const int quad = lane >> 4;
    const int lr = lane & 15;

    // A-staging: 2 rows/thread, 32-elem halves
    const int ra = tid >> 1;
    const int ahalf = tid & 1;
    const int tokA0 = pair_tok[pairBase + min(ra, cnt - 1)];
    const int tokA1 = pair_tok[pairBase + min(ra + 128, cnt - 1)];
    const uint16_t* aSrc0 = x_bf + (size_t)tokA0 * DDIM + ahalf * 32;
    const uint16_t* aSrc1 = x_bf + (size_t)tokA1 * DDIM + ahalf * 32;

    // B-staging indices
    const int kb = tid >> 2;      // fp32 path: k-row
    const int ng = tid & 3;       // fp32 path: n-group of 16
    const int rb = tid >> 2;      // bf16 path: n-row
    const int qk = tid & 3;       // bf16 path: k-group of 16
    const float* w1Base = W1f + (size_t)e * DDIM * FDIM + n0 + ng * 16;
    const float* w3Base = W3f + (size_t)e * DDIM * FDIM + n0 + ng * 16;
    const uint16_t* w1tBase = W1t + (size_t)e * DDIM * FDIM + (size_t)(n0 + rb) * DDIM + qk * 16;
    const uint16_t* w3tBase = W3t + (size_t)e * DDIM * FDIM + (size_t)(n0 + rb) * DDIM + qk * 16;

    f32x4 accG[4][4], accU[4][4];
#pragma unroll
    for (int i = 0; i < 4; i++)
#pragma unroll
        for (int j = 0; j < 4; j++) {
            accG[i][j] = (f32x4){0.f, 0.f, 0.f, 0.f};
            accU[i][j] = (f32x4){0.f, 0.f, 0.f, 0.f};
        }

    for (int k0 = 0; k0 < DDIM; k0 += BK) {
        __syncthreads();
        {   // stage A
            const uint4* s0 = (const uint4*)(aSrc0 + k0);
            uint4 v0 = s0[0], v1 = s0[1], v2 = s0[2], v3 = s0[3];
            const uint4* s1 = (const uint4*)(aSrc1 + k0);
            uint4 w0 = s1[0], w1 = s1[1], w2 = s1[2], w3 = s1[3];
            uint4* d0 = (uint4*)&As[ra][ahalf * 32];
            d0[0] = v0; d0[1] = v1; d0[2] = v2; d0[3] = v3;
            uint4* d1 = (uint4*)&As[ra + 128][ahalf * 32];
            d1[0] = w0; d1[1] = w1; d1[2] = w2; d1[3] = w3;
        }
        if constexpr (BF16W) {
            const uint4* s1 = (const uint4*)(w1tBase + k0);
            uint4 a0 = s1[0], a1 = s1[1];
            *(uint4*)&B1s[rb][qk * 16] = a0; *(uint4*)&B1s[rb][qk * 16 + 8] = a1;
            const uint4* s3 = (const uint4*)(w3tBase + k0);
            uint4 b0 = s3[0], b1 = s3[1];
            *(uint4*)&B3s[rb][qk * 16] = b0; *(uint4*)&B3s[rb][qk * 16 + 8] = b1;
        } else {
            const float4* s1 = (const float4*)(w1Base + (size_t)(k0 + kb) * FDIM);
            float4 c0 = s1[0], c1 = s1[1], c2 = s1[2], c3 = s1[3];
            uint16_t* bc = &B1s[ng * 16][kb];
            bc[0*BPAD]=f2bf(c0.x); bc[1*BPAD]=f2bf(c0.y); bc[2*BPAD]=f2bf(c0.z); bc[3*BPAD]=f2bf(c0.w);
            bc[4*BPAD]=f2bf(c1.x); bc[5*BPAD]=f2bf(c1.y); bc[6*BPAD]=f2bf(c1.z); bc[7*BPAD]=f2bf(c1.w);
            bc[8*BPAD]=f2bf(c2.x); bc[9*BPAD]=f2bf(c2.y); bc[10*BPAD]=f2bf(c2.z); bc[11*BPAD]=f2bf(c2.w);
            bc[12*BPAD]=f2bf(c3.x); bc[13*BPAD]=f2bf(c3.y); bc[14*BPAD]=f2bf(c3.z); bc[15*BPAD]=f2bf(c3.w);
            const float4* s3 = (const float4*)(w3Base + (size_t)(k0 + kb) * FDIM);
            float4 d0 = s3[0], d1 = s3[1], d2 = s3[2], d3 = s3[3];
            uint16_t* dc = &B3s[ng * 16][kb];
            dc[0*BPAD]=f2bf(d0.x); dc[1*BPAD]=f2bf(d0.y); dc[2*BPAD]=f2bf(d0.z); dc[3*BPAD]=f2bf(d0.w);
            dc[4*BPAD]=f2bf(d1.x); dc[5*BPAD]=f2bf(d1.y); dc[6*BPAD]=f2bf(d1.z); dc[7*BPAD]=f2bf(d1.w);
            dc[8*BPAD]=f2bf(d2.x); dc[9*BPAD]=f2bf(d2.y); dc[10*BPAD]=f2bf(d2.z); dc[11*BPAD]=f2bf(d2.w);
            dc[12*BPAD]=f2bf(d3.x); dc[13*BPAD]=f2bf(d3.y); dc[14*BPAD]=f2bf(d3.z); dc[15*BPAD]=f2bf(d3.w);
        }
        __syncthreads();
#pragma unroll
        for (int kk = 0; kk < BK; kk += 32) {
            short8 af[4];
#pragma unroll
            for (int mi = 0; mi < 4; mi++)
                af[mi] = *(const short8*)&As[wave * 64 + mi * 16 + lr][kk + quad * 8];
#pragma unroll
            for (int ni = 0; ni < 4; ni++) {
                short8 b1 = *(const short8*)&B1s[ni * 16 + lr][kk + quad * 8];
                short8 b3 = *(const short8*)&B3s[ni * 16 + lr][kk + quad * 8];
#pragma unroll
                for (int mi = 0; mi < 4; mi++) {
                    accG[mi][ni] = __builtin_amdgcn_mfma_f32_16x16x32_bf16(af[mi], b1, accG[mi][ni], 0, 0, 0);
                    accU[mi][ni] = __builtin_amdgcn_mfma_f32_16x16x32_bf16(af[mi], b3, accU[mi][ni], 0, 0, 0);
                }
            }
        }
    }
#pragma unroll
    for (int mi = 0; mi < 4; mi++) {
#pragma unroll
        for (int r = 0; r < 4; r++) {
            int rowLocal = wave * 64 + mi * 16 + quad * 4 + r;
            if (rowLocal < cnt) {
                uint16_t* dst = h + (size_t)(pairBase + rowLocal) * FDIM + n0 + lr;
#pragma unroll
                for (int ni = 0; ni < 4; ni++) {
                    float g = accG[mi][ni][r];
                    float u = accU[mi][ni][r];
                    float hv = (g / (1.f + __expf(-g))) * u;
                    dst[ni * 16] = f2bf(hv);
                }
            }
        }
    }
}

// ---------------- pass B: out += weight * (h @ W2) ----------------
template<bool BF16W>
__global__ __launch_bounds__(256, 2)
void expert_down_kernel(const uint16_t* __restrict__ h,
                        const float* __restrict__ W2f, const uint16_t* __restrict__ W2t,
                        const int* __restrict__ counts, const int* __restrict__ offs,
                        const int* __restrict__ pair_tok, const float* __restrict__ pair_w,
                        float* __restrict__ out) {
    const int e = blockIdx.z;
    const int tile = blockIdx.y;
    const int n0 = blockIdx.x * BN;     // d columns
    const int cntAll = counts[e];
    if (tile * BM >= cntAll) return;
    const int cnt = min(BM, cntAll - tile * BM);
    const int pairBase = offs[e] + tile * BM;

    __shared__ uint16_t As[BM][APAD];
    __shared__ uint16_t Bs[BN][BPAD];

    const int tid = threadIdx.x;
    const int wave = tid >> 6;
    const int lane = tid & 63;
    const int quad = lane >> 4;
    const int lr = lane & 15;

    const int ra = tid >> 1;
    const int ahalf = tid & 1;
    const uint16_t* aSrc0 = h + (size_t)(pairBase + min(ra, cnt - 1)) * FDIM + ahalf * 32;
    const uint16_t* aSrc1 = h + (size_t)(pairBase + min(ra + 128, cnt - 1)) * FDIM + ahalf * 32;

    const int kb = tid >> 2;
    const int ng = tid & 3;
    const int rb = tid >> 2;
    const int qk = tid & 3;
    const float* w2Base = W2f + (size_t)e * FDIM * DDIM + n0 + ng * 16;
    const uint16_t* w2tBase = W2t + (size_t)e * FDIM * DDIM + (size_t)(n0 + rb) * FDIM + qk * 16;

    f32x4 acc[4][4];
#pragma unroll
    for (int i = 0; i < 4; i++)
#pragma unroll
        for (int j = 0; j < 4; j++) acc[i][j] = (f32x4){0.f, 0.f, 0.f, 0.f};

    for (int k0 = 0; k0 < FDIM; k0 += BK) {
        __syncthreads();
        {
            const uint4* s0 = (const uint4*)(aSrc0 + k0);
            uint4 v0 = s0[0], v1 = s0[1], v2 = s0[2], v3 = s0[3];
            const uint4* s1 = (const uint4*)(aSrc1 + k0);
            uint4 w0 = s1[0], w1 = s1[1], w2 = s1[2], w3 = s1[3];
            uint4* d0 = (uint4*)&As[ra][ahalf * 32];
            d0[0] = v0; d0[1] = v1; d0[2] = v2; d0[3] = v3;
            uint4* d1 = (uint4*)&As[ra + 128][ahalf * 32];
            d1[0] = w0; d1[1] = w1; d1[2] = w2; d1[3] = w3;
        }
        if constexpr (BF16W) {
            const uint4* s2 = (const uint4*)(w2tBase + k0);
            uint4 a0 = s2[0], a1 = s2[1];
            *(uint4*)&Bs[rb][qk * 16] = a0; *(uint4*)&Bs[rb][qk * 16 + 8] = a1;
        } else {
            const float4* s2 = (const float4*)(w2Base + (size_t)(k0 + kb) * DDIM);
            float4 c0 = s2[0], c1 = s2[1], c2 = s2[2], c3 = s2[3];
            uint16_t* bc = &Bs[ng * 16][kb];
            bc[0*BPAD]=f2bf(c0.x); bc[1*BPAD]=f2bf(c0.y); bc[2*BPAD]=f2bf(c0.z); bc[3*BPAD]=f2bf(c0.w);
            bc[4*BPAD]=f2bf(c1.x); bc[5*BPAD]=f2bf(c1.y); bc[6*BPAD]=f2bf(c1.z); bc[7*BPAD]=f2bf(c1.w);
            bc[8*BPAD]=f2bf(c2.x); bc[9*BPAD]=f2bf(c2.y); bc[10*BPAD]=f2bf(c2.z); bc[11*BPAD]=f2bf(c2.w);
            bc[12*BPAD]=f2bf(c3.x); bc[13*BPAD]=f2bf(c3.y); bc[14*BPAD]=f2bf(c3.z); bc[15*BPAD]=f2bf(c3.w);
        }
        __syncthreads();
#pragma unroll
        for (int kk = 0; kk < BK; kk += 32) {
            short8 af[4];
#pragma unroll
            for (int mi = 0; mi < 4; mi++)
                af[mi] = *(const short8*)&As[wave * 64 + mi * 16 + lr][kk + quad * 8];
#pragma unroll
            for (int ni = 0; ni < 4; ni++) {
                short8 b = *(const short8*)&Bs[ni * 16 + lr][kk + quad * 8];
#pragma unroll
                for (int mi = 0; mi < 4; mi++)
                    acc[mi][ni] = __builtin_amdgcn_mfma_f32_16x16x32_bf16(af[mi], b, acc[mi][ni], 0, 0, 0);
            }
        }
    }
#pragma unroll
    for (int mi = 0; mi < 4; mi++) {
#pragma unroll
        for (int r = 0; r < 4; r++) {
            int rowLocal = wave * 64 + mi * 16 + quad * 4 + r;
            if (rowLocal < cnt) {
                int pi = pairBase + rowLocal;
                int tok = pair_tok[pi];
                float w = pair_w[pi];
                float* dst = out + (size_t)tok * DDIM + n0 + lr;
#pragma unroll
                for (int ni = 0; ni < 4; ni++)
                    atomicAdd(&dst[ni * 16], acc[mi][ni][r] * w);
            }
        }
    }
}

extern "C" void kernel_launch(void* const* d_in, const int* in_sizes, int n_in,
                              void* d_out, int out_size, void* d_ws, size_t ws_size,
                              hipStream_t stream) {
    (void)in_sizes; (void)n_in;
    const float* x  = (const float*)d_in[0];
    const float* Wr = (const float*)d_in[1];
    const float* W1 = (const float*)d_in[2];
    const float* W3 = (const float*)d_in[3];
    const float* W2 = (const float*)d_in[4];
    float* out = (float*)d_out;

    char* ws = (char*)d_ws;
    size_t off = 0;
    int*      counts    = (int*)(ws + off);  off += 64;
    int*      offs      = (int*)(ws + off);  off += 64;
    int*      fill      = (int*)(ws + off);  off += 128;   // pad to 256
    int*      top_e     = (int*)(ws + off);  off += 4 * NPAIR;
    float*    top_w     = (float*)(ws + off); off += 4 * NPAIR;
    int*      pair_tok  = (int*)(ws + off);  off += 4 * NPAIR;
    float*    pair_w    = (float*)(ws + off); off += 4 * NPAIR;
    int*      cnt_part  = (int*)(ws + off);  off += 4 * RT_BLOCKS * NEXP;
    float*    us_part   = (float*)(ws + off); off += 4 * RT_BLOCKS * NEXP;
    uint16_t* x_bf      = (uint16_t*)(ws + off); off += (size_t)2 * NTOK * DDIM;
    uint16_t* h         = (uint16_t*)(ws + off); off += (size_t)2 * NPAIR * FDIM;
    const size_t wBytes = (size_t)2 * NEXP * DDIM * FDIM;   // 67.1 MB per matrix (bf16)
    uint16_t* W1t = (uint16_t*)(ws + off);
    uint16_t* W3t = (uint16_t*)(ws + off + wBytes);
    uint16_t* W2t = (uint16_t*)(ws + off + 2 * wBytes);
    const bool bf16w = ws_size >= off + 3 * wBytes;

    hipMemsetAsync(ws, 0, 256, stream);                                   // counts/offs/fill
    hipMemsetAsync(d_out, 0, (size_t)out_size * sizeof(float), stream);   // out accumulators

    xcast_kernel<<<NTOK * DDIM / 1024, 256, 0, stream>>>(x, x_bf);
    router_kernel<<<RT_BLOCKS, 256, 0, stream>>>(x, Wr, cnt_part, us_part, top_e, top_w);
    finalize_kernel<<<1, 64, 0, stream>>>(cnt_part, us_part, counts, offs, out);
    scatter_kernel<<<NTOK / 256, 256, 0, stream>>>(top_e, top_w, offs, fill, pair_tok, pair_w);

    dim3 gA(FDIM / BN, NTOK / BM, NEXP);   // (f-tiles, max token-tiles, experts)
    dim3 gB(DDIM / BN, NTOK / BM, NEXP);   // (d-tiles, max token-tiles, experts)
    if (bf16w) {
        transpose_cast_kernel<<<dim3(FDIM / 32, DDIM / 32, NEXP), 256, 0, stream>>>(W1, W1t, DDIM, FDIM);
        transpose_cast_kernel<<<dim3(FDIM / 32, DDIM / 32, NEXP), 256, 0, stream>>>(W3, W3t, DDIM, FDIM);
        transpose_cast_kernel<<<dim3(DDIM / 32, FDIM / 32, NEXP), 256, 0, stream>>>(W2, W2t, FDIM, DDIM);
        expert_up_kernel<true><<<gA, 256, 0, stream>>>(x_bf, nullptr, nullptr, W1t, W3t,
                                                       counts, offs, pair_tok, h);
        expert_down_kernel<true><<<gB, 256, 0, stream>>>(h, nullptr, W2t,
                                                         counts, offs, pair_tok, pair_w, out);
    } else {
        expert_up_kernel<false><<<gA, 256, 0, stream>>>(x_bf, W1, W3, nullptr, nullptr,
                                                        counts, offs, pair_tok, h);
        expert_down_kernel<false><<<gB, 256, 0, stream>>>(h, W2, nullptr,
                                                          counts, offs, pair_tok, pair_w, out);
    }
}

// Round 3
// 805.999 us; speedup vs baseline: 1.5684x; 1.0378x over previous
//
#include <hip/hip_runtime.h>
#include <hip/hip_bf16.h>
#include <stdint.h>
#include <math.h>

#define NTOK 4096   // B*T
#define DDIM 1024
#define FDIM 4096
#define NEXP 8
#define NPAIR 8192  // NTOK * TOP_K

#define BM 256
#define BN 64
#define BK 64       // 8 chunks of 8 bf16 (16B) per row

#define RT_TPW 8
#define RT_BLOCKS (NTOK / (4 * RT_TPW))   // 128

using short8 = __attribute__((ext_vector_type(8))) short;
using f32x4  = __attribute__((ext_vector_type(4))) float;

__device__ __forceinline__ uint16_t f2bf(float f) {
    union { float f; uint32_t u; } v; v.f = f;
    uint32_t r = v.u + 0x7FFFu + ((v.u >> 16) & 1u);   // RNE
    return (uint16_t)(r >> 16);
}

// async global->LDS, 16B per lane; LDS dest = wave-uniform base + lane*16
__device__ __forceinline__ void async16(const void* g, void* l) {
    __builtin_amdgcn_global_load_lds((const __attribute__((address_space(1))) void*)g,
                                     (__attribute__((address_space(3))) void*)l,
                                     16, 0, 0);
}

// ---------------- router ----------------
__global__ void router_kernel(const float* __restrict__ x, const float* __restrict__ Wr,
                              int* __restrict__ cnt_part, float* __restrict__ us_part,
                              int* __restrict__ top_e, float* __restrict__ top_w) {
    __shared__ float us[NEXP];
    __shared__ int cs[NEXP];
    const int tid = threadIdx.x;
    const int wv = tid >> 6;
    const int lane = tid & 63;
    if (tid < NEXP) { us[tid] = 0.f; cs[tid] = 0; }
    __syncthreads();

    for (int i = 0; i < RT_TPW; i++) {
        const int t = blockIdx.x * (4 * RT_TPW) + wv * RT_TPW + i;
        float acc[NEXP];
#pragma unroll
        for (int e = 0; e < NEXP; e++) acc[e] = 0.f;
        const float* xr = x + (size_t)t * DDIM;
        for (int d = lane; d < DDIM; d += 64) {
            float xv = xr[d];
            const float* wr = Wr + (size_t)d * NEXP;
#pragma unroll
            for (int e = 0; e < NEXP; e++) acc[e] += xv * wr[e];
        }
#pragma unroll
        for (int e = 0; e < NEXP; e++) {
#pragma unroll
            for (int off = 32; off > 0; off >>= 1) acc[e] += __shfl_xor(acc[e], off, 64);
        }
        if (lane == 0) {
            int i0 = 0;
#pragma unroll
            for (int e = 1; e < NEXP; e++) if (acc[e] > acc[i0]) i0 = e;
            int i1 = -1;
#pragma unroll
            for (int e = 0; e < NEXP; e++) {
                if (e == i0) continue;
                if (i1 < 0 || acc[e] > acc[i1]) i1 = e;
            }
            float v0 = acc[i0], v1 = acc[i1];
            float e1 = __expf(v1 - v0);
            float inv = 1.f / (1.f + e1);
            top_e[t * 2 + 0] = i0; top_e[t * 2 + 1] = i1;
            top_w[t * 2 + 0] = inv; top_w[t * 2 + 1] = e1 * inv;
            atomicAdd(&cs[i0], 1);
            atomicAdd(&cs[i1], 1);
            float m = acc[0];
#pragma unroll
            for (int e = 1; e < NEXP; e++) m = fmaxf(m, acc[e]);
            float p[NEXP]; float s = 0.f;
#pragma unroll
            for (int e = 0; e < NEXP; e++) { p[e] = __expf(acc[e] - m); s += p[e]; }
            float is = 1.f / s;
#pragma unroll
            for (int e = 0; e < NEXP; e++) atomicAdd(&us[e], p[e] * is);
        }
    }
    __syncthreads();
    if (tid < NEXP) {
        cnt_part[blockIdx.x * NEXP + tid] = cs[tid];
        us_part[blockIdx.x * NEXP + tid] = us[tid];
    }
}

__global__ void finalize_kernel(const int* __restrict__ cnt_part, const float* __restrict__ us_part,
                                int* __restrict__ counts, int* __restrict__ offs,
                                float* __restrict__ out) {
    __shared__ int c[NEXP];
    __shared__ float u[NEXP];
    const int tid = threadIdx.x;
    if (tid < NEXP) {
        int csum = 0; float usum = 0.f;
        for (int b = 0; b < RT_BLOCKS; b++) {
            csum += cnt_part[b * NEXP + tid];
            usum += us_part[b * NEXP + tid];
        }
        counts[tid] = csum; c[tid] = csum; u[tid] = usum;
    }
    __syncthreads();
    if (tid == 0) {
        int s = 0; float l = 0.f;
#pragma unroll
        for (int e = 0; e < NEXP; e++) {
            offs[e] = s; s += c[e];
            float uu = u[e] * (1.f / (float)NTOK);
            l += uu * uu;
        }
        out[(size_t)NTOK * DDIM] = (float)NEXP * l;
    }
}

__global__ void xcast_kernel(const float* __restrict__ x, uint16_t* __restrict__ xb) {
    int i = blockIdx.x * 256 + threadIdx.x;
    float4 v = ((const float4*)x)[i];
    ushort4 o;
    o.x = f2bf(v.x); o.y = f2bf(v.y); o.z = f2bf(v.z); o.w = f2bf(v.w);
    ((ushort4*)xb)[i] = o;
}

// ---------------- transpose+cast: [e][R][C] fp32 -> [e][C][R] bf16, 64x64 tiles ----------------
// LDS tile logical [c][r], physical 16B-chunk swizzle: phys = (r>>3) ^ (c&7)
__global__ void transpose_cast_kernel(const float* __restrict__ in, uint16_t* __restrict__ outp,
                                      int R, int C) {
    __shared__ uint16_t tile[64 * 64];
    const int e = blockIdx.z;
    const float* src = in + (size_t)e * R * C;
    uint16_t* dst = outp + (size_t)e * R * C;
    const int r0 = blockIdx.y * 64, c0 = blockIdx.x * 64;
    const int t = threadIdx.x;
    {
        const int rb = t >> 4;          // 0..15
        const int c4 = t & 15;          // col group of 4
#pragma unroll
        for (int i = 0; i < 4; i++) {
            const int r = rb + i * 16;
            float4 v = *(const float4*)(src + (size_t)(r0 + r) * C + c0 + c4 * 4);
            const int rc = (r >> 3);    // chunk index of r
            const int re = (r & 7);     // elem within chunk
#pragma unroll
            for (int j = 0; j < 4; j++) {
                const int c = c4 * 4 + j;
                float fv = (j == 0) ? v.x : (j == 1) ? v.y : (j == 2) ? v.z : v.w;
                tile[c * 64 + ((rc ^ (c & 7)) << 3) + re] = f2bf(fv);
            }
        }
    }
    __syncthreads();
    {
        const int cr = t >> 3;          // 0..31 (+32 on 2nd iter): output row (= input col)
        const int ch = t & 7;           // chunk of 8 elems along r
#pragma unroll
        for (int i = 0; i < 2; i++) {
            const int c = cr + i * 32;
            uint4 v = *(const uint4*)&tile[c * 64 + ((ch ^ (c & 7)) << 3)];
            *(uint4*)(dst + (size_t)(c0 + c) * R + r0 + ch * 8) = v;
        }
    }
}

__global__ void scatter_kernel(const int* __restrict__ top_e, const float* __restrict__ top_w,
                               const int* __restrict__ offs, int* __restrict__ fill,
                               int* __restrict__ pair_tok, float* __restrict__ pair_w) {
    __shared__ int lcnt[NEXP];
    __shared__ int lbase[NEXP];
    const int tid = threadIdx.x;
    const int t = blockIdx.x * 256 + tid;
    if (tid < NEXP) lcnt[tid] = 0;
    __syncthreads();
    int e0 = top_e[t * 2 + 0], e1 = top_e[t * 2 + 1];
    int r0 = atomicAdd(&lcnt[e0], 1);
    int r1 = atomicAdd(&lcnt[e1], 1);
    __syncthreads();
    if (tid < NEXP) lbase[tid] = atomicAdd(&fill[tid], lcnt[tid]);
    __syncthreads();
    int p0 = offs[e0] + lbase[e0] + r0;
    int p1 = offs[e1] + lbase[e1] + r1;
    pair_tok[p0] = t; pair_w[p0] = top_w[t * 2 + 0];
    pair_tok[p1] = t; pair_w[p1] = top_w[t * 2 + 1];
}

// ---------------- pass A: h = silu(x@W1) * (x@W3) ----------------
// LDS layout (A and B): row-major [row][64], 16B chunk swizzled phys = log ^ (row&7)
__global__ __launch_bounds__(256, 2)
void expert_up_kernel(const uint16_t* __restrict__ x_bf,
                      const uint16_t* __restrict__ W1t, const uint16_t* __restrict__ W3t,
                      const int* __restrict__ counts, const int* __restrict__ offs,
                      const int* __restrict__ pair_tok, uint16_t* __restrict__ h) {
    const int e = blockIdx.z;
    const int tile = blockIdx.y;
    const int n0 = blockIdx.x * BN;
    const int cntAll = counts[e];
    if (tile * BM >= cntAll) return;
    const int cnt = min(BM, cntAll - tile * BM);
    const int pairBase = offs[e] + tile * BM;

    __shared__ uint16_t As[BM * BK];
    __shared__ uint16_t B1s[BN * BK];
    __shared__ uint16_t B3s[BN * BK];

    const int tid = threadIdx.x;
    const int wave = tid >> 6;
    const int lane = tid & 63;
    const int quad = lane >> 4;
    const int lr = lane & 15;
    const int sub = lane >> 3;        // 0..7
    const int swoff = (((lane & 7) ^ sub) << 3);   // swizzled source offset (elems)

    // token row per A-staging issue (rows fixed across K)
    int tokr[8];
#pragma unroll
    for (int i = 0; i < 8; i++) {
        int row = wave * 64 + i * 8 + sub;
        tokr[i] = pair_tok[pairBase + min(row, cnt - 1)];
    }
    const uint16_t* w1p = W1t + (size_t)e * DDIM * FDIM;
    const uint16_t* w3p = W3t + (size_t)e * DDIM * FDIM;

    f32x4 accG[4][4], accU[4][4];
#pragma unroll
    for (int i = 0; i < 4; i++)
#pragma unroll
        for (int j = 0; j < 4; j++) {
            accG[i][j] = (f32x4){0.f, 0.f, 0.f, 0.f};
            accU[i][j] = (f32x4){0.f, 0.f, 0.f, 0.f};
        }

    for (int k0 = 0; k0 < DDIM; k0 += BK) {
        __syncthreads();
#pragma unroll
        for (int i = 0; i < 8; i++)     // A: 8 rows per issue
            async16(x_bf + (size_t)tokr[i] * DDIM + k0 + swoff,
                    &As[(wave * 64 + i * 8) * BK] + lane * 8);
#pragma unroll
        for (int j = 0; j < 2; j++) {   // B1/B3: 8 rows per issue
            int n = wave * 16 + j * 8 + sub;
            async16(w1p + (size_t)(n0 + n) * DDIM + k0 + swoff,
                    &B1s[(wave * 16 + j * 8) * BK] + lane * 8);
            async16(w3p + (size_t)(n0 + n) * DDIM + k0 + swoff,
                    &B3s[(wave * 16 + j * 8) * BK] + lane * 8);
        }
        __syncthreads();
#pragma unroll
        for (int kk = 0; kk < BK; kk += 32) {
            const int lc = (kk >> 3) + quad;      // logical chunk
            short8 af[4];
#pragma unroll
            for (int mi = 0; mi < 4; mi++) {
                int R = wave * 64 + mi * 16 + lr;
                af[mi] = *(const short8*)&As[R * BK + ((lc ^ (lr & 7)) << 3)];
            }
#pragma unroll
            for (int ni = 0; ni < 4; ni++) {
                int n = ni * 16 + lr;
                short8 b1 = *(const short8*)&B1s[n * BK + ((lc ^ (lr & 7)) << 3)];
                short8 b3 = *(const short8*)&B3s[n * BK + ((lc ^ (lr & 7)) << 3)];
#pragma unroll
                for (int mi = 0; mi < 4; mi++) {
                    accG[mi][ni] = __builtin_amdgcn_mfma_f32_16x16x32_bf16(af[mi], b1, accG[mi][ni], 0, 0, 0);
                    accU[mi][ni] = __builtin_amdgcn_mfma_f32_16x16x32_bf16(af[mi], b3, accU[mi][ni], 0, 0, 0);
                }
            }
        }
    }
#pragma unroll
    for (int mi = 0; mi < 4; mi++) {
#pragma unroll
        for (int r = 0; r < 4; r++) {
            int rowLocal = wave * 64 + mi * 16 + quad * 4 + r;
            if (rowLocal < cnt) {
                uint16_t* dst = h + (size_t)(pairBase + rowLocal) * FDIM + n0 + lr;
#pragma unroll
                for (int ni = 0; ni < 4; ni++) {
                    float g = accG[mi][ni][r];
                    float u = accU[mi][ni][r];
                    float hv = (g / (1.f + __expf(-g))) * u;
                    dst[ni * 16] = f2bf(hv);
                }
            }
        }
    }
}

// ---------------- pass B: out += weight * (h @ W2) ----------------
__global__ __launch_bounds__(256, 3)
void expert_down_kernel(const uint16_t* __restrict__ h, const uint16_t* __restrict__ W2t,
                        const int* __restrict__ counts, const int* __restrict__ offs,
                        const int* __restrict__ pair_tok, const float* __restrict__ pair_w,
                        float* __restrict__ out) {
    const int e = blockIdx.z;
    const int tile = blockIdx.y;
    const int n0 = blockIdx.x * BN;     // d columns
    const int cntAll = counts[e];
    if (tile * BM >= cntAll) return;
    const int cnt = min(BM, cntAll - tile * BM);
    const int pairBase = offs[e] + tile * BM;

    __shared__ uint16_t As[BM * BK];
    __shared__ uint16_t Bs[BN * BK];

    const int tid = threadIdx.x;
    const int wave = tid >> 6;
    const int lane = tid & 63;
    const int quad = lane >> 4;
    const int lr = lane & 15;
    const int sub = lane >> 3;
    const int swoff = (((lane & 7) ^ sub) << 3);

    int hrow[8];
#pragma unroll
    for (int i = 0; i < 8; i++) {
        int row = wave * 64 + i * 8 + sub;
        hrow[i] = pairBase + min(row, cnt - 1);
    }
    const uint16_t* w2p = W2t + (size_t)e * FDIM * DDIM;

    f32x4 acc[4][4];
#pragma unroll
    for (int i = 0; i < 4; i++)
#pragma unroll
        for (int j = 0; j < 4; j++) acc[i][j] = (f32x4){0.f, 0.f, 0.f, 0.f};

    for (int k0 = 0; k0 < FDIM; k0 += BK) {
        __syncthreads();
#pragma unroll
        for (int i = 0; i < 8; i++)
            async16(h + (size_t)hrow[i] * FDIM + k0 + swoff,
                    &As[(wave * 64 + i * 8) * BK] + lane * 8);
#pragma unroll
        for (int j = 0; j < 2; j++) {
            int n = wave * 16 + j * 8 + sub;
            async16(w2p + (size_t)(n0 + n) * FDIM + k0 + swoff,
                    &Bs[(wave * 16 + j * 8) * BK] + lane * 8);
        }
        __syncthreads();
#pragma unroll
        for (int kk = 0; kk < BK; kk += 32) {
            const int lc = (kk >> 3) + quad;
            short8 af[4];
#pragma unroll
            for (int mi = 0; mi < 4; mi++) {
                int R = wave * 64 + mi * 16 + lr;
                af[mi] = *(const short8*)&As[R * BK + ((lc ^ (lr & 7)) << 3)];
            }
#pragma unroll
            for (int ni = 0; ni < 4; ni++) {
                int n = ni * 16 + lr;
                short8 b = *(const short8*)&Bs[n * BK + ((lc ^ (lr & 7)) << 3)];
#pragma unroll
                for (int mi = 0; mi < 4; mi++)
                    acc[mi][ni] = __builtin_amdgcn_mfma_f32_16x16x32_bf16(af[mi], b, acc[mi][ni], 0, 0, 0);
            }
        }
    }
#pragma unroll
    for (int mi = 0; mi < 4; mi++) {
#pragma unroll
        for (int r = 0; r < 4; r++) {
            int rowLocal = wave * 64 + mi * 16 + quad * 4 + r;
            if (rowLocal < cnt) {
                int pi = pairBase + rowLocal;
                int tok = pair_tok[pi];
                float w = pair_w[pi];
                float* dst = out + (size_t)tok * DDIM + n0 + lr;
#pragma unroll
                for (int ni = 0; ni < 4; ni++)
                    atomicAdd(&dst[ni * 16], acc[mi][ni][r] * w);
            }
        }
    }
}

extern "C" void kernel_launch(void* const* d_in, const int* in_sizes, int n_in,
                              void* d_out, int out_size, void* d_ws, size_t ws_size,
                              hipStream_t stream) {
    (void)in_sizes; (void)n_in; (void)ws_size;
    const float* x  = (const float*)d_in[0];
    const float* Wr = (const float*)d_in[1];
    const float* W1 = (const float*)d_in[2];
    const float* W3 = (const float*)d_in[3];
    const float* W2 = (const float*)d_in[4];
    float* out = (float*)d_out;

    char* ws = (char*)d_ws;
    size_t off = 0;
    int*      counts    = (int*)(ws + off);  off += 64;
    int*      offs      = (int*)(ws + off);  off += 64;
    int*      fill      = (int*)(ws + off);  off += 128;
    int*      top_e     = (int*)(ws + off);  off += 4 * NPAIR;
    float*    top_w     = (float*)(ws + off); off += 4 * NPAIR;
    int*      pair_tok  = (int*)(ws + off);  off += 4 * NPAIR;
    float*    pair_w    = (float*)(ws + off); off += 4 * NPAIR;
    int*      cnt_part  = (int*)(ws + off);  off += 4 * RT_BLOCKS * NEXP;
    float*    us_part   = (float*)(ws + off); off += 4 * RT_BLOCKS * NEXP;
    uint16_t* x_bf      = (uint16_t*)(ws + off); off += (size_t)2 * NTOK * DDIM;   // 8 MB
    uint16_t* h         = (uint16_t*)(ws + off); off += (size_t)2 * NPAIR * FDIM;  // 67 MB
    const size_t wBytes = (size_t)2 * NEXP * DDIM * FDIM;   // 67.1 MB per matrix (bf16)
    uint16_t* W1t = (uint16_t*)(ws + off);
    uint16_t* W3t = (uint16_t*)(ws + off + wBytes);
    uint16_t* W2t = (uint16_t*)(ws + off + 2 * wBytes);     // total ~277 MB (verified fits R2)

    hipMemsetAsync(ws, 0, 256, stream);
    hipMemsetAsync(d_out, 0, (size_t)out_size * sizeof(float), stream);

    xcast_kernel<<<NTOK * DDIM / 1024, 256, 0, stream>>>(x, x_bf);
    router_kernel<<<RT_BLOCKS, 256, 0, stream>>>(x, Wr, cnt_part, us_part, top_e, top_w);
    finalize_kernel<<<1, 64, 0, stream>>>(cnt_part, us_part, counts, offs, out);
    scatter_kernel<<<NTOK / 256, 256, 0, stream>>>(top_e, top_w, offs, fill, pair_tok, pair_w);

    transpose_cast_kernel<<<dim3(FDIM / 64, DDIM / 64, NEXP), 256, 0, stream>>>(W1, W1t, DDIM, FDIM);
    transpose_cast_kernel<<<dim3(FDIM / 64, DDIM / 64, NEXP), 256, 0, stream>>>(W3, W3t, DDIM, FDIM);
    transpose_cast_kernel<<<dim3(DDIM / 64, FDIM / 64, NEXP), 256, 0, stream>>>(W2, W2t, FDIM, DDIM);

    dim3 gA(FDIM / BN, NTOK / BM, NEXP);
    expert_up_kernel<<<gA, 256, 0, stream>>>(x_bf, W1t, W3t, counts, offs, pair_tok, h);
    dim3 gB(DDIM / BN, NTOK / BM, NEXP);
    expert_down_kernel<<<gB, 256, 0, stream>>>(h, W2t, counts, offs, pair_tok, pair_w, out);
}